// Round 14
// baseline (170.093 us; speedup 1.0000x reference)
//
#include <hip/hip_runtime.h>

#define B_ 2
#define C_ 256
#define H_ 56
#define W_ 56
#define N_ 64
#define M_ 8
#define P_ 7
#define R_ (N_ + N_*M_)          // 576 rois per image
#define BR_ (B_*R_)              // 1152
#define Y2_ (H_/2)               // 28 y-row pairs
#define SCTX_ 4                  // column chunks per ctx roi (box roi = whole)
#define JPN_ (1 + (M_)*SCTX_)    // 33 jobs per (b,n) -> 4224 blocks
#define WROW_ 8                  // padded weight-row stride (7 used + col7 = 0)

typedef _Float16 half2v __attribute__((ext_vector_type(2)));

#if __has_builtin(__builtin_amdgcn_fdot2)
#define FDOT2(a, b, c) __builtin_amdgcn_fdot2((a), (b), (c), false)
#else
static __device__ __forceinline__ float FDOT2(half2v a, half2v b, float c) {
    return fmaf((float)a.x, (float)b.x, fmaf((float)a.y, (float)b.y, c));
}
#endif

// ---- workspace layout (dword-element offsets) ----
#define F_FMT3 0
#define N_FMT3 (B_*Y2_*W_*C_)                // 802,816  f16 y-pair-packed fmap [b][y2][x][c]
#define F_WY2  (F_FMT3 + N_FMT3)
#define N_WY2  (BR_*Y2_*WROW_)               // 258,048  half2 y-weights [y2][py], col7=0
#define F_AXD  (F_WY2 + N_WY2)
#define N_AXD  (BR_*W_*WROW_)                // 516,096  fp32 x-weights [x][px] (ctx /M), col7=0
#define F_OUTS (F_AXD + N_AXD)
#define N_OUTS (B_*N_*49*C_)                 // 1,605,632 staging out [b][n][py][px][c]
#define E_XLO  (F_OUTS + N_OUTS)             // int region
#define E_XHI  (E_XLO + BR_)
#define E_YLO  (E_XHI + BR_)
#define E_YHI  (E_YLO + BR_)
#define WS_ELEMS (E_YHI + BR_)               // ~12.8 MB

// fused prep kernel block ranges
#define PREP_T   (B_*Y2_*2)                  // 112: f16 pack-transpose (x-halves)
#define RPWB_    16                          // rois per weight block
#define PREP_WB  (BR_/RPWB_)                 // 72 weight blocks
#define PREP_W   (PREP_T + PREP_WB)          // 184
#define PREP_N   (PREP_W + 784)              // zero outS: 784*2048 floats

// ---------------------------------------------------------------------------
// k_prep: three jobs in one dispatch.
//   [0,112):    fm -> fmt3 packed half2(rows 2y2,2y2+1)   (R12-verified)
//   [112,184):  weights, LDS-staged: 16 rois/block; per roi zero a 3.6KB LDS
//               tile cooperatively, 14 threads fill samples into COLUMN-
//               PRIVATE cells (thread p owns column p -> race-free, no
//               atomics), 256 threads write wy2/axd fully coalesced.
//   [184,968):  zero outS
__global__ __launch_bounds__(256) void k_prep(const float* __restrict__ fm,
                                              const float* __restrict__ boxes,
                                              const float* __restrict__ gt,
                                              float* __restrict__ ws_f) {
    int bid = blockIdx.x;
    int tid = (int)threadIdx.x;

    if (bid < PREP_T) {                      // ---- pack-transpose ----
        int xh = bid & 1;
        int y2 = (bid >> 1) % Y2_;
        int b  = bid / (2 * Y2_);
        int c  = tid;                        // all 256 channels
        int x0 = xh * (W_ / 2);
        const float4* r0 = (const float4*)(fm + (((size_t)b * C_ + c) * H_ + 2 * y2) * W_ + x0);
        const float4* r1 = (const float4*)(fm + (((size_t)b * C_ + c) * H_ + 2 * y2 + 1) * W_ + x0);
        unsigned int* dst = (unsigned int*)ws_f + F_FMT3 +
                            (((size_t)b * Y2_ + y2) * W_ + x0) * (size_t)C_ + c;
#pragma unroll
        for (int x4 = 0; x4 < W_ / 8; ++x4) {   // 7 float4 = 28 columns
            float4 a = r0[x4];
            float4 bb = r1[x4];
            half2v h0; h0.x = (_Float16)a.x; h0.y = (_Float16)bb.x;
            half2v h1; h1.x = (_Float16)a.y; h1.y = (_Float16)bb.y;
            half2v h2; h2.x = (_Float16)a.z; h2.y = (_Float16)bb.z;
            half2v h3; h3.x = (_Float16)a.w; h3.y = (_Float16)bb.w;
            dst[(x4 * 4 + 0) * C_] = __builtin_bit_cast(unsigned int, h0);
            dst[(x4 * 4 + 1) * C_] = __builtin_bit_cast(unsigned int, h1);
            dst[(x4 * 4 + 2) * C_] = __builtin_bit_cast(unsigned int, h2);
            dst[(x4 * 4 + 3) * C_] = __builtin_bit_cast(unsigned int, h3);
        }
        return;
    }

    if (bid < PREP_W) {                      // ---- weights (LDS-staged) ----
        __shared__ float wy[H_][WROW_];      // 1792 B  fp32 y-weights
        __shared__ float ax[W_][WROW_];      // 1792 B  fp32 x-weights
        int wb = bid - PREP_T;
        int* ip = (int*)ws_f;

        for (int rr = 0; rr < RPWB_; ++rr) {
            int br = wb * RPWB_ + rr;
            int r  = br % R_;
            int b  = br / R_;

            // box coords (wave-uniform; computed by all threads)
            float x1, y1, x2, y2;
            if (r < N_) {
                const float* bp = boxes + ((size_t)b * N_ + r) * 4;
                x1 = bp[0]; y1 = bp[1]; x2 = bp[2]; y2 = bp[3];
            } else {
                int q = r - N_;
                int n = q / M_, m = q % M_;
                const float* bp = boxes + ((size_t)b * N_ + n) * 4;
                const float* gp = gt + ((size_t)b * M_ + m) * 4;
                x1 = fminf(bp[0], gp[0]); y1 = fminf(bp[1], gp[1]);
                x2 = fmaxf(bp[2], gp[2]); y2 = fmaxf(bp[3], gp[3]);
            }
            float rw = fmaxf(x2 - x1, 1.0f);
            float rh = fmaxf(y2 - y1, 1.0f);

            // zero LDS tiles (coalesced, ~4 stores/thread)
            for (int e = tid; e < H_ * WROW_; e += 256) ((float*)wy)[e] = 0.0f;
            for (int e = tid; e < W_ * WROW_; e += 256) ((float*)ax)[e] = 0.0f;
            __syncthreads();

            // samples: y-axis by threads 0..6 (p=tid), x-axis by 64..70
            // (p=tid-64). Column-private writes -> no races.
            if (tid < P_) {
                int p = tid;
                float bin = rh / 7.0f;
                float gf  = ceilf(bin);
                int   g   = (int)gf;
                float ivg = 1.0f / gf;
                float start = y1 + (float)p * bin;
                for (int s = 0; s < g; ++s) {
                    float coord = start + ((float)s + 0.5f) * bin * ivg;
                    if (coord < -1.0f || coord > (float)H_) continue;
                    float cc = fmaxf(coord, 0.0f);
                    int low = (int)floorf(cc);
                    int high; float l;
                    if (low >= H_ - 1) { low = H_ - 1; high = H_ - 1; l = 0.0f; }
                    else               { high = low + 1; l = cc - (float)low; }
                    wy[low][p]  += (1.0f - l) * ivg;
                    wy[high][p] += l * ivg;
                }
            } else if (tid >= 64 && tid < 64 + P_) {
                int p = tid - 64;
                float bin = rw / 7.0f;
                float gf  = ceilf(bin);
                int   g   = (int)gf;
                float ivg = 1.0f / gf;
                float fs  = (r < N_) ? ivg : ivg * (1.0f / (float)M_);
                float start = x1 + (float)p * bin;
                for (int s = 0; s < g; ++s) {
                    float coord = start + ((float)s + 0.5f) * bin * ivg;
                    if (coord < -1.0f || coord > (float)W_) continue;
                    float cc = fmaxf(coord, 0.0f);
                    int low = (int)floorf(cc);
                    int high; float l;
                    if (low >= W_ - 1) { low = W_ - 1; high = W_ - 1; l = 0.0f; }
                    else               { high = low + 1; l = cc - (float)low; }
                    ax[low][p]  += (1.0f - l) * fs;
                    ax[high][p] += l * fs;
                }
            } else if (tid == 128) {
                ip[E_XLO + br] = min(max((int)floorf(fmaxf(x1, 0.0f)), 0), W_ - 1);
                ip[E_XHI + br] = min(max((int)floorf(x1 + rw) + 1, 0), W_ - 1) + 1;
                ip[E_YLO + br] = min(max((int)floorf(fmaxf(y1, 0.0f)), 0), H_ - 1);
                ip[E_YHI + br] = min(max((int)floorf(y1 + rh) + 1, 0), H_ - 1) + 1;
            }
            __syncthreads();

            // coalesced writes: wy2 (224 half2 words) + axd (448 dwords)
            unsigned int* wrow = (unsigned int*)ws_f + F_WY2 + (size_t)br * (Y2_ * WROW_);
            if (tid < Y2_ * WROW_) {
                int q2 = tid >> 3, col = tid & 7;
                half2v h;
                if (col < P_) { h.x = (_Float16)wy[2 * q2][col]; h.y = (_Float16)wy[2 * q2 + 1][col]; }
                else          { h.x = (_Float16)0.0f; h.y = (_Float16)0.0f; }
                wrow[tid] = __builtin_bit_cast(unsigned int, h);
            }
            float* arow = ws_f + F_AXD + (size_t)br * (W_ * WROW_);
            for (int e = tid; e < W_ * WROW_; e += 256) {
                int col = e & 7;
                arow[e] = (col < P_) ? ax[e >> 3][col] : 0.0f;
            }
            __syncthreads();
        }
        return;
    }

    {                                        // ---- zero outS ----
        int t = (bid - PREP_W) * 256 + tid;  // < 200,704
        float4 z = {0.0f, 0.0f, 0.0f, 0.0f};
        float4* dst = (float4*)(ws_f + F_OUTS);
        dst[t * 2]     = z;
        dst[t * 2 + 1] = z;
    }
}

// ---------------------------------------------------------------------------
// k_main: R12-verified body (x-quad x y-pair dot2, 2-deep pipeline, plain
// (b,n,j) mapping — R13 swizzle was neutral). 256 thr = 4 waves = 4 channel
// groups. Epilogue: live-px coalesced atomics into outS [py][px][c].
__global__ __launch_bounds__(256, 4) void k_main(const float* __restrict__ ws_f,
                                                 float* __restrict__ outs) {
    const int* ip = (const int*)ws_f;
    int bid = blockIdx.x;
    int j   = bid % JPN_;
    int n   = (bid / JPN_) & (N_ - 1);
    int b   = bid / (JPN_ * N_);
    int k, s;
    if (j == 0) { k = 0; s = 0; }
    else        { k = 1 + ((j - 1) >> 2); s = (j - 1) & 3; }
    int tid  = (int)threadIdx.x;
    int lane = tid & 63;
    int rg   = tid >> 6;
    int c    = rg * 64 + lane;

    int r  = (k == 0) ? n : (N_ + n * M_ + (k - 1));
    int br = b * R_ + r;

    int xlo = ip[E_XLO + br];
    int xhi = ip[E_XHI + br];
    int ylo = ip[E_YLO + br];
    int yhi = ip[E_YHI + br];
    int xs, xe;
    if (k == 0) { xs = xlo; xe = xhi; }
    else {
        int cw = (xhi - xlo + SCTX_ - 1) >> 2;
        xs = xlo + s * cw;
        xe = min(xs + cw, xhi);
    }
    if (xs >= xe) return;                    // no barriers in kernel -> safe

    int ylo2 = ylo >> 1;                     // pair range covering [ylo,yhi)
    int yhi2 = (yhi + 1) >> 1;               // extra rows have zero weight

    const unsigned int* wy2 = (const unsigned int*)ws_f + F_WY2 + (size_t)br * (Y2_ * WROW_);
    const float*        axd = ws_f + F_AXD + (size_t)br * (W_ * WROW_);
    const unsigned int* f3  = (const unsigned int*)ws_f + F_FMT3 + (size_t)b * (Y2_ * W_ * C_);

    float acc[49];
#pragma unroll
    for (int q = 0; q < 49; ++q) acc[q] = 0.0f;
    int live = 0;

    for (int x = xs; x < xe; x += 4) {
        float cs[4][P_];
#pragma unroll
        for (int i = 0; i < 4; ++i)
#pragma unroll
            for (int py = 0; py < P_; ++py) cs[i][py] = 0.0f;

        // x+1..x+3 / one-y2-row over-reads past roi edge are harmless: all
        // addresses stay inside d_ws; garbage never enters acc (gated on xe;
        // over-read y-row values are dropped when the loop exits).
        const unsigned int* col = f3 + ((size_t)(ylo2 * W_ + x)) * C_ + c;
        const uint4* wp = (const uint4*)(wy2 + ylo2 * WROW_);
        unsigned int d0 = col[0];
        unsigned int d1 = col[C_];
        unsigned int d2 = col[2 * C_];
        unsigned int d3 = col[3 * C_];
        uint4 wa = wp[0];
        uint4 wb = wp[1];
        for (int y2 = ylo2; y2 < yhi2; ++y2) {
            const unsigned int* nc = col + W_ * C_;
            unsigned int e0 = nc[0];                   // prefetch next iter
            unsigned int e1 = nc[C_];
            unsigned int e2 = nc[2 * C_];
            unsigned int e3 = nc[3 * C_];
            uint4 na = wp[2];
            uint4 nb = wp[3];

            half2v v0 = __builtin_bit_cast(half2v, d0);
            half2v v1 = __builtin_bit_cast(half2v, d1);
            half2v v2 = __builtin_bit_cast(half2v, d2);
            half2v v3 = __builtin_bit_cast(half2v, d3);
            half2v w[7];
            w[0] = __builtin_bit_cast(half2v, wa.x);
            w[1] = __builtin_bit_cast(half2v, wa.y);
            w[2] = __builtin_bit_cast(half2v, wa.z);
            w[3] = __builtin_bit_cast(half2v, wa.w);
            w[4] = __builtin_bit_cast(half2v, wb.x);
            w[5] = __builtin_bit_cast(half2v, wb.y);
            w[6] = __builtin_bit_cast(half2v, wb.z);
#pragma unroll
            for (int py = 0; py < P_; ++py) {
                cs[0][py] = FDOT2(w[py], v0, cs[0][py]);
                cs[1][py] = FDOT2(w[py], v1, cs[1][py]);
                cs[2][py] = FDOT2(w[py], v2, cs[2][py]);
                cs[3][py] = FDOT2(w[py], v3, cs[3][py]);
            }
            d0 = e0; d1 = e1; d2 = e2; d3 = e3;
            wa = na; wb = nb;
            col = nc; wp += 2;
        }

        // ---- x-stage (fp32, exact weights) ----
#pragma unroll
        for (int i = 0; i < 4; ++i) {
            if (x + i < xe) {                         // wave-uniform branch
                float av[8];
                *(float4*)(&av[0]) = *(const float4*)(axd + (x + i) * WROW_);
                *(float4*)(&av[4]) = *(const float4*)(axd + (x + i) * WROW_ + 4);
#pragma unroll
                for (int px = 0; px < P_; ++px) {
                    float w = av[px];
                    if (w != 0.0f) {
                        live |= 1 << px;
#pragma unroll
                        for (int py = 0; py < P_; ++py)
                            acc[py * P_ + px] = fmaf(w, cs[i][py], acc[py * P_ + px]);
                    }
                }
            }
        }
    }

    // ---- epilogue: live-px coalesced wave-atomics into outS ----
    float* os = outs + ((size_t)b * N_ + n) * (49 * C_) + c;
#pragma unroll
    for (int px = 0; px < P_; ++px) {
        if (live & (1 << px)) {
#pragma unroll
            for (int py = 0; py < P_; ++py)
                atomicAdd(os + (py * P_ + px) * C_, acc[py * P_ + px]);
        }
    }
}

// ---------------------------------------------------------------------------
// k_final: outS [b][n][py][px][c] -> out [b][n][c][py][px] via padded LDS.
__global__ __launch_bounds__(256) void k_final(const float* __restrict__ outs,
                                               float* __restrict__ out) {
    __shared__ float t[49 * 257];        // pad 257: conflict-free transpose read
    int bn  = blockIdx.x;                // 0..B*N-1
    int tid = (int)threadIdx.x;
    const float* src = outs + (size_t)bn * (49 * C_);
    for (int e = tid; e < 49 * C_; e += 256) {
        int q = e >> 8, c = e & 255;
        t[q * 257 + c] = src[e];         // coalesced read
    }
    __syncthreads();
    float* dst = out + (size_t)bn * (C_ * 49);
    for (int e = tid; e < C_ * 49; e += 256) {
        int c = e / 49, q = e % 49;
        dst[e] = t[q * 257 + c];         // coalesced write
    }
}

// ---------------------------------------------------------------------------
extern "C" void kernel_launch(void* const* d_in, const int* in_sizes, int n_in,
                              void* d_out, int out_size, void* d_ws, size_t ws_size,
                              hipStream_t stream) {
    const float* fm    = (const float*)d_in[0];
    const float* boxes = (const float*)d_in[1];
    const float* gt    = (const float*)d_in[2];
    float* ws_f = (float*)d_ws;
    float* out  = (float*)d_out;
    float* outs = ws_f + F_OUTS;

    k_prep<<<PREP_N, 256, 0, stream>>>(fm, boxes, gt, ws_f);
    k_main<<<B_ * N_ * JPN_, 256, 0, stream>>>(ws_f, outs);
    k_final<<<B_ * N_, 256, 0, stream>>>(outs, out);
}

// Round 15
// 166.205 us; speedup vs baseline: 1.0234x; 1.0234x over previous
//
#include <hip/hip_runtime.h>

#define B_ 2
#define C_ 256
#define H_ 56
#define W_ 56
#define N_ 64
#define M_ 8
#define P_ 7
#define R_ (N_ + N_*M_)          // 576 rois per image
#define BR_ (B_*R_)              // 1152
#define Y2_ (H_/2)               // 28 y-row pairs
#define Y4_ (H_/4)               // 14 y-row quads
#define SCTX_ 4                  // column chunks per ctx roi (box roi = whole)
#define JPN_ (1 + (M_)*SCTX_)    // 33 jobs per (b,n) -> 4224 blocks
#define WROW_ 8                  // padded weight-row stride (7 used + col7 = 0)

typedef _Float16 half2v __attribute__((ext_vector_type(2)));

#if __has_builtin(__builtin_amdgcn_fdot2)
#define FDOT2(a, b, c) __builtin_amdgcn_fdot2((a), (b), (c), false)
#else
static __device__ __forceinline__ float FDOT2(half2v a, half2v b, float c) {
    return fmaf((float)a.x, (float)b.x, fmaf((float)a.y, (float)b.y, c));
}
#endif

// ---- workspace layout (dword-element offsets) ----
#define F_FMT4 0
#define N_FMT4 (B_*Y4_*W_*C_*2)              // 802,816 dw  f16 y-QUAD-packed fmap
                                             //   uint2 per (b,y4,x,c): .x=half2(r0,r1) .y=half2(r2,r3)
#define F_WY2  (F_FMT4 + N_FMT4)
#define N_WY2  (BR_*Y2_*WROW_)               // 258,048  half2 y-weights [y2][py], col7=0
#define F_AXD  (F_WY2 + N_WY2)
#define N_AXD  (BR_*W_*WROW_)                // 516,096  fp32 x-weights [x][px] (ctx /M), col7=0
#define F_OUTS (F_AXD + N_AXD)
#define N_OUTS (B_*N_*49*C_)                 // 1,605,632 staging out [b][n][py][px][c]
#define E_XLO  (F_OUTS + N_OUTS)             // int region
#define E_XHI  (E_XLO + BR_)
#define E_YLO  (E_XHI + BR_)
#define E_YHI  (E_YLO + BR_)
#define WS_ELEMS (E_YHI + BR_)               // ~12.8 MB

// fused prep kernel block ranges
#define PREP_T   (B_*Y4_*2)                  // 56: y4 pack-transpose (x-halves)
#define RPWB_    16                          // rois per weight block
#define PREP_WB  (BR_/RPWB_)                 // 72 weight blocks
#define PREP_W   (PREP_T + PREP_WB)          // 128
#define PREP_N   (PREP_W + 784)              // zero outS: 784*2048 floats

// ---------------------------------------------------------------------------
// k_prep: three jobs in one dispatch.
//   [0,56):    fm -> fmt4: uint2 per (y4,x,c) = half2(r0,r1), half2(r2,r3)
//   [56,128):  weights, LDS-staged (R14-verified): 16 rois/block, column-
//              private LDS cells, coalesced wy2/axd writes.
//   [128,912): zero outS
__global__ __launch_bounds__(256) void k_prep(const float* __restrict__ fm,
                                              const float* __restrict__ boxes,
                                              const float* __restrict__ gt,
                                              float* __restrict__ ws_f) {
    int bid = blockIdx.x;
    int tid = (int)threadIdx.x;

    if (bid < PREP_T) {                      // ---- y4 pack-transpose ----
        int xh = bid & 1;
        int y4 = (bid >> 1) % Y4_;
        int b  = bid / (2 * Y4_);
        int c  = tid;                        // all 256 channels
        int x0 = xh * (W_ / 2);
        const float* base = fm + (((size_t)b * C_ + c) * H_ + 4 * y4) * W_ + x0;
        const float4* r0 = (const float4*)(base);
        const float4* r1 = (const float4*)(base + W_);
        const float4* r2 = (const float4*)(base + 2 * W_);
        const float4* r3 = (const float4*)(base + 3 * W_);
        uint2* dst = (uint2*)ws_f + (((size_t)b * Y4_ + y4) * W_ + x0) * (size_t)C_ + c;
#pragma unroll
        for (int x4 = 0; x4 < W_ / 8; ++x4) {   // 7 float4 = 28 columns
            float4 a = r0[x4], e = r1[x4], f = r2[x4], g = r3[x4];
            half2v lo, hi; uint2 o;
            lo.x = (_Float16)a.x; lo.y = (_Float16)e.x;
            hi.x = (_Float16)f.x; hi.y = (_Float16)g.x;
            o.x = __builtin_bit_cast(unsigned int, lo);
            o.y = __builtin_bit_cast(unsigned int, hi);
            dst[(x4 * 4 + 0) * C_] = o;
            lo.x = (_Float16)a.y; lo.y = (_Float16)e.y;
            hi.x = (_Float16)f.y; hi.y = (_Float16)g.y;
            o.x = __builtin_bit_cast(unsigned int, lo);
            o.y = __builtin_bit_cast(unsigned int, hi);
            dst[(x4 * 4 + 1) * C_] = o;
            lo.x = (_Float16)a.z; lo.y = (_Float16)e.z;
            hi.x = (_Float16)f.z; hi.y = (_Float16)g.z;
            o.x = __builtin_bit_cast(unsigned int, lo);
            o.y = __builtin_bit_cast(unsigned int, hi);
            dst[(x4 * 4 + 2) * C_] = o;
            lo.x = (_Float16)a.w; lo.y = (_Float16)e.w;
            hi.x = (_Float16)f.w; hi.y = (_Float16)g.w;
            o.x = __builtin_bit_cast(unsigned int, lo);
            o.y = __builtin_bit_cast(unsigned int, hi);
            dst[(x4 * 4 + 3) * C_] = o;
        }
        return;
    }

    if (bid < PREP_W) {                      // ---- weights (LDS-staged) ----
        __shared__ float wy[H_][WROW_];      // 1792 B  fp32 y-weights
        __shared__ float ax[W_][WROW_];      // 1792 B  fp32 x-weights
        int wb = bid - PREP_T;
        int* ip = (int*)ws_f;

        for (int rr = 0; rr < RPWB_; ++rr) {
            int br = wb * RPWB_ + rr;
            int r  = br % R_;
            int b  = br / R_;

            float x1, y1, x2, y2;
            if (r < N_) {
                const float* bp = boxes + ((size_t)b * N_ + r) * 4;
                x1 = bp[0]; y1 = bp[1]; x2 = bp[2]; y2 = bp[3];
            } else {
                int q = r - N_;
                int n = q / M_, m = q % M_;
                const float* bp = boxes + ((size_t)b * N_ + n) * 4;
                const float* gp = gt + ((size_t)b * M_ + m) * 4;
                x1 = fminf(bp[0], gp[0]); y1 = fminf(bp[1], gp[1]);
                x2 = fmaxf(bp[2], gp[2]); y2 = fmaxf(bp[3], gp[3]);
            }
            float rw = fmaxf(x2 - x1, 1.0f);
            float rh = fmaxf(y2 - y1, 1.0f);

            for (int e = tid; e < H_ * WROW_; e += 256) ((float*)wy)[e] = 0.0f;
            for (int e = tid; e < W_ * WROW_; e += 256) ((float*)ax)[e] = 0.0f;
            __syncthreads();

            if (tid < P_) {                  // y samples, column-private
                int p = tid;
                float bin = rh / 7.0f;
                float gf  = ceilf(bin);
                int   g   = (int)gf;
                float ivg = 1.0f / gf;
                float start = y1 + (float)p * bin;
                for (int s = 0; s < g; ++s) {
                    float coord = start + ((float)s + 0.5f) * bin * ivg;
                    if (coord < -1.0f || coord > (float)H_) continue;
                    float cc = fmaxf(coord, 0.0f);
                    int low = (int)floorf(cc);
                    int high; float l;
                    if (low >= H_ - 1) { low = H_ - 1; high = H_ - 1; l = 0.0f; }
                    else               { high = low + 1; l = cc - (float)low; }
                    wy[low][p]  += (1.0f - l) * ivg;
                    wy[high][p] += l * ivg;
                }
            } else if (tid >= 64 && tid < 64 + P_) {   // x samples
                int p = tid - 64;
                float bin = rw / 7.0f;
                float gf  = ceilf(bin);
                int   g   = (int)gf;
                float ivg = 1.0f / gf;
                float fs  = (r < N_) ? ivg : ivg * (1.0f / (float)M_);
                float start = x1 + (float)p * bin;
                for (int s = 0; s < g; ++s) {
                    float coord = start + ((float)s + 0.5f) * bin * ivg;
                    if (coord < -1.0f || coord > (float)W_) continue;
                    float cc = fmaxf(coord, 0.0f);
                    int low = (int)floorf(cc);
                    int high; float l;
                    if (low >= W_ - 1) { low = W_ - 1; high = W_ - 1; l = 0.0f; }
                    else               { high = low + 1; l = cc - (float)low; }
                    ax[low][p]  += (1.0f - l) * fs;
                    ax[high][p] += l * fs;
                }
            } else if (tid == 128) {
                ip[E_XLO + br] = min(max((int)floorf(fmaxf(x1, 0.0f)), 0), W_ - 1);
                ip[E_XHI + br] = min(max((int)floorf(x1 + rw) + 1, 0), W_ - 1) + 1;
                ip[E_YLO + br] = min(max((int)floorf(fmaxf(y1, 0.0f)), 0), H_ - 1);
                ip[E_YHI + br] = min(max((int)floorf(y1 + rh) + 1, 0), H_ - 1) + 1;
            }
            __syncthreads();

            unsigned int* wrow = (unsigned int*)ws_f + F_WY2 + (size_t)br * (Y2_ * WROW_);
            if (tid < Y2_ * WROW_) {
                int q2 = tid >> 3, col = tid & 7;
                half2v h;
                if (col < P_) { h.x = (_Float16)wy[2 * q2][col]; h.y = (_Float16)wy[2 * q2 + 1][col]; }
                else          { h.x = (_Float16)0.0f; h.y = (_Float16)0.0f; }
                wrow[tid] = __builtin_bit_cast(unsigned int, h);
            }
            float* arow = ws_f + F_AXD + (size_t)br * (W_ * WROW_);
            for (int e = tid; e < W_ * WROW_; e += 256) {
                int col = e & 7;
                arow[e] = (col < P_) ? ax[e >> 3][col] : 0.0f;
            }
            __syncthreads();
        }
        return;
    }

    {                                        // ---- zero outS ----
        int t = (bid - PREP_W) * 256 + tid;  // < 200,704
        float4 z = {0.0f, 0.0f, 0.0f, 0.0f};
        float4* dst = (float4*)(ws_f + F_OUTS);
        dst[t * 2]     = z;
        dst[t * 2 + 1] = z;
    }
}

// ---------------------------------------------------------------------------
// k_main: block = (b, n, j) (R6-proven chunking). 256 thr = 4 waves = 4
// channel groups. Weights (wy2 896B + axd 1792B) staged into LDS once per
// block; in-loop weight reads are wave-uniform ds_read_b128 broadcasts.
// Inner loop: x-QUAD x y-QUAD: 4 dwordx2 data loads (4 rows/lane, 512B/wave)
// + 4 LDS b128 feed 56 dot2. VMEM instrs per 4 rows: 12 (R12) -> 4.
// Epilogue: live-px coalesced atomics into outS [py][px][c].
__global__ __launch_bounds__(256, 4) void k_main(const float* __restrict__ ws_f,
                                                 float* __restrict__ outs) {
    __shared__ unsigned int lds_wy[Y2_ * WROW_];   //  896 B
    __shared__ float        lds_ax[W_ * WROW_];    // 1792 B

    const int* ip = (const int*)ws_f;
    int bid = blockIdx.x;
    int j   = bid % JPN_;
    int n   = (bid / JPN_) & (N_ - 1);
    int b   = bid / (JPN_ * N_);
    int k, s;
    if (j == 0) { k = 0; s = 0; }
    else        { k = 1 + ((j - 1) >> 2); s = (j - 1) & 3; }
    int tid  = (int)threadIdx.x;
    int lane = tid & 63;
    int rg   = tid >> 6;
    int c    = rg * 64 + lane;

    int r  = (k == 0) ? n : (N_ + n * M_ + (k - 1));
    int br = b * R_ + r;

    int xlo = ip[E_XLO + br];
    int xhi = ip[E_XHI + br];
    int ylo = ip[E_YLO + br];
    int yhi = ip[E_YHI + br];
    int xs, xe;
    if (k == 0) { xs = xlo; xe = xhi; }
    else {
        int cw = (xhi - xlo + SCTX_ - 1) >> 2;
        xs = xlo + s * cw;
        xe = min(xs + cw, xhi);
    }
    if (xs >= xe) return;                    // block-uniform -> barrier-safe

    // stage this roi's weights into LDS (coalesced, once per block)
    {
        const unsigned int* wsrc = (const unsigned int*)ws_f + F_WY2 + (size_t)br * (Y2_ * WROW_);
        if (tid < Y2_ * WROW_) lds_wy[tid] = wsrc[tid];
        const float* asrc = ws_f + F_AXD + (size_t)br * (W_ * WROW_);
        for (int e = tid; e < W_ * WROW_; e += 256) lds_ax[e] = asrc[e];
    }
    __syncthreads();

    int ylo4 = ylo >> 2;                     // quad range covering [ylo,yhi)
    int yhi4 = (yhi + 3) >> 2;               // extra rows have zero weight

    const uint2* f4 = (const uint2*)ws_f + (size_t)b * (Y4_ * W_ * C_);

    float acc[49];
#pragma unroll
    for (int q = 0; q < 49; ++q) acc[q] = 0.0f;
    int live = 0;

    for (int x = xs; x < xe; x += 4) {
        float cs[4][P_];
#pragma unroll
        for (int i = 0; i < 4; ++i)
#pragma unroll
            for (int py = 0; py < P_; ++py) cs[i][py] = 0.0f;

        // x+1..x+3 over-reads past xe/roi edge stay inside the fmt4 region
        // or spill into F_WY2 (in-ws); garbage never enters acc (gated on xe).
        const uint2* cp = f4 + ((size_t)(ylo4 * W_ + x)) * C_ + c;
        for (int y4 = ylo4; y4 < yhi4; ++y4) {
            uint2 d0 = cp[0];
            uint2 d1 = cp[C_];
            uint2 d2 = cp[2 * C_];
            uint2 d3 = cp[3 * C_];
            // weight rows: pair0 = rows(4y4,4y4+1) matches d.x; pair1 = d.y
            uint4 wa0 = *(const uint4*)&lds_wy[(2 * y4) * WROW_];
            uint4 wb0 = *(const uint4*)&lds_wy[(2 * y4) * WROW_ + 4];
            uint4 wa1 = *(const uint4*)&lds_wy[(2 * y4 + 1) * WROW_];
            uint4 wb1 = *(const uint4*)&lds_wy[(2 * y4 + 1) * WROW_ + 4];
            half2v w0[7], w1[7];
            w0[0] = __builtin_bit_cast(half2v, wa0.x);
            w0[1] = __builtin_bit_cast(half2v, wa0.y);
            w0[2] = __builtin_bit_cast(half2v, wa0.z);
            w0[3] = __builtin_bit_cast(half2v, wa0.w);
            w0[4] = __builtin_bit_cast(half2v, wb0.x);
            w0[5] = __builtin_bit_cast(half2v, wb0.y);
            w0[6] = __builtin_bit_cast(half2v, wb0.z);
            w1[0] = __builtin_bit_cast(half2v, wa1.x);
            w1[1] = __builtin_bit_cast(half2v, wa1.y);
            w1[2] = __builtin_bit_cast(half2v, wa1.z);
            w1[3] = __builtin_bit_cast(half2v, wa1.w);
            w1[4] = __builtin_bit_cast(half2v, wb1.x);
            w1[5] = __builtin_bit_cast(half2v, wb1.y);
            w1[6] = __builtin_bit_cast(half2v, wb1.z);
            half2v v0a = __builtin_bit_cast(half2v, d0.x);
            half2v v0b = __builtin_bit_cast(half2v, d0.y);
            half2v v1a = __builtin_bit_cast(half2v, d1.x);
            half2v v1b = __builtin_bit_cast(half2v, d1.y);
            half2v v2a = __builtin_bit_cast(half2v, d2.x);
            half2v v2b = __builtin_bit_cast(half2v, d2.y);
            half2v v3a = __builtin_bit_cast(half2v, d3.x);
            half2v v3b = __builtin_bit_cast(half2v, d3.y);
#pragma unroll
            for (int py = 0; py < P_; ++py) {
                cs[0][py] = FDOT2(w1[py], v0b, FDOT2(w0[py], v0a, cs[0][py]));
                cs[1][py] = FDOT2(w1[py], v1b, FDOT2(w0[py], v1a, cs[1][py]));
                cs[2][py] = FDOT2(w1[py], v2b, FDOT2(w0[py], v2a, cs[2][py]));
                cs[3][py] = FDOT2(w1[py], v3b, FDOT2(w0[py], v3a, cs[3][py]));
            }
            cp += W_ * C_;
        }

        // ---- x-stage (fp32, exact weights from LDS) ----
#pragma unroll
        for (int i = 0; i < 4; ++i) {
            if (x + i < xe) {                         // wave-uniform branch
                float av[8];
                *(float4*)(&av[0]) = *(const float4*)&lds_ax[(x + i) * WROW_];
                *(float4*)(&av[4]) = *(const float4*)&lds_ax[(x + i) * WROW_ + 4];
#pragma unroll
                for (int px = 0; px < P_; ++px) {
                    float w = av[px];
                    if (w != 0.0f) {
                        live |= 1 << px;
#pragma unroll
                        for (int py = 0; py < P_; ++py)
                            acc[py * P_ + px] = fmaf(w, cs[i][py], acc[py * P_ + px]);
                    }
                }
            }
        }
    }

    // ---- epilogue: live-px coalesced wave-atomics into outS ----
    float* os = outs + ((size_t)b * N_ + n) * (49 * C_) + c;
#pragma unroll
    for (int px = 0; px < P_; ++px) {
        if (live & (1 << px)) {
#pragma unroll
            for (int py = 0; py < P_; ++py)
                atomicAdd(os + (py * P_ + px) * C_, acc[py * P_ + px]);
        }
    }
}

// ---------------------------------------------------------------------------
// k_final: outS [b][n][py][px][c] -> out [b][n][c][py][px] via padded LDS.
__global__ __launch_bounds__(256) void k_final(const float* __restrict__ outs,
                                               float* __restrict__ out) {
    __shared__ float t[49 * 257];        // pad 257: conflict-free transpose read
    int bn  = blockIdx.x;                // 0..B*N-1
    int tid = (int)threadIdx.x;
    const float* src = outs + (size_t)bn * (49 * C_);
    for (int e = tid; e < 49 * C_; e += 256) {
        int q = e >> 8, c = e & 255;
        t[q * 257 + c] = src[e];         // coalesced read
    }
    __syncthreads();
    float* dst = out + (size_t)bn * (C_ * 49);
    for (int e = tid; e < C_ * 49; e += 256) {
        int c = e / 49, q = e % 49;
        dst[e] = t[q * 257 + c];         // coalesced write
    }
}

// ---------------------------------------------------------------------------
extern "C" void kernel_launch(void* const* d_in, const int* in_sizes, int n_in,
                              void* d_out, int out_size, void* d_ws, size_t ws_size,
                              hipStream_t stream) {
    const float* fm    = (const float*)d_in[0];
    const float* boxes = (const float*)d_in[1];
    const float* gt    = (const float*)d_in[2];
    float* ws_f = (float*)d_ws;
    float* out  = (float*)d_out;
    float* outs = ws_f + F_OUTS;

    k_prep<<<PREP_N, 256, 0, stream>>>(fm, boxes, gt, ws_f);
    k_main<<<B_ * N_ * JPN_, 256, 0, stream>>>(ws_f, outs);
    k_final<<<B_ * N_, 256, 0, stream>>>(outs, out);
}

// Round 16
// 148.812 us; speedup vs baseline: 1.1430x; 1.1169x over previous
//
#include <hip/hip_runtime.h>

#define B_ 2
#define C_ 256
#define H_ 56
#define W_ 56
#define N_ 64
#define M_ 8
#define P_ 7
#define R_ (N_ + N_*M_)          // 576 rois per image
#define BR_ (B_*R_)              // 1152
#define Y2_ (H_/2)               // 28 y-row pairs
#define Y4_ (H_/4)               // 14 y-row quads
#define SCTX_ 4                  // column chunks per ctx roi (box roi = whole)
#define JPN_ (1 + (M_)*SCTX_)    // 33 jobs per (b,n) -> 4224 blocks
#define WROW_ 8                  // padded weight-row stride (7 used + col7 = 0)

typedef _Float16 half2v __attribute__((ext_vector_type(2)));

#if __has_builtin(__builtin_amdgcn_fdot2)
#define FDOT2(a, b, c) __builtin_amdgcn_fdot2((a), (b), (c), false)
#else
static __device__ __forceinline__ float FDOT2(half2v a, half2v b, float c) {
    return fmaf((float)a.x, (float)b.x, fmaf((float)a.y, (float)b.y, c));
}
#endif

// ---- workspace layout (dword-element offsets) ----
#define F_FMT4 0
#define N_FMT4 (B_*Y4_*W_*C_*2)              // 802,816 dw  f16 y-QUAD-packed fmap
                                             //   uint2 per (b,y4,x,c): .x=half2(r0,r1) .y=half2(r2,r3)
#define F_OUTS (F_FMT4 + N_FMT4)
#define N_OUTS (B_*N_*49*C_)                 // 1,605,632 staging out [b][n][py][px][c]
#define WS_ELEMS (F_OUTS + N_OUTS)           // ~9.6 MB

// prep kernel block ranges (weights job DELETED — k_main generates in-block)
#define PREP_T (B_*Y4_*2)                    // 56: y4 pack-transpose (x-halves)
#define PREP_N (PREP_T + 784)                // 840: + zero outS (784*2048 floats)

// ---------------------------------------------------------------------------
// k_prep: two jobs in one dispatch.
//   [0,56):   fm -> fmt4: uint2 per (y4,x,c) = half2(r0,r1), half2(r2,r3)
//   [56,840): zero outS
__global__ __launch_bounds__(256) void k_prep(const float* __restrict__ fm,
                                              float* __restrict__ ws_f) {
    int bid = blockIdx.x;
    int tid = (int)threadIdx.x;

    if (bid < PREP_T) {                      // ---- y4 pack-transpose ----
        int xh = bid & 1;
        int y4 = (bid >> 1) % Y4_;
        int b  = bid / (2 * Y4_);
        int c  = tid;                        // all 256 channels
        int x0 = xh * (W_ / 2);
        const float* base = fm + (((size_t)b * C_ + c) * H_ + 4 * y4) * W_ + x0;
        const float4* r0 = (const float4*)(base);
        const float4* r1 = (const float4*)(base + W_);
        const float4* r2 = (const float4*)(base + 2 * W_);
        const float4* r3 = (const float4*)(base + 3 * W_);
        uint2* dst = (uint2*)ws_f + (((size_t)b * Y4_ + y4) * W_ + x0) * (size_t)C_ + c;
#pragma unroll
        for (int x4 = 0; x4 < W_ / 8; ++x4) {   // 7 float4 = 28 columns
            float4 a = r0[x4], e = r1[x4], f = r2[x4], g = r3[x4];
            half2v lo, hi; uint2 o;
            lo.x = (_Float16)a.x; lo.y = (_Float16)e.x;
            hi.x = (_Float16)f.x; hi.y = (_Float16)g.x;
            o.x = __builtin_bit_cast(unsigned int, lo);
            o.y = __builtin_bit_cast(unsigned int, hi);
            dst[(x4 * 4 + 0) * C_] = o;
            lo.x = (_Float16)a.y; lo.y = (_Float16)e.y;
            hi.x = (_Float16)f.y; hi.y = (_Float16)g.y;
            o.x = __builtin_bit_cast(unsigned int, lo);
            o.y = __builtin_bit_cast(unsigned int, hi);
            dst[(x4 * 4 + 1) * C_] = o;
            lo.x = (_Float16)a.z; lo.y = (_Float16)e.z;
            hi.x = (_Float16)f.z; hi.y = (_Float16)g.z;
            o.x = __builtin_bit_cast(unsigned int, lo);
            o.y = __builtin_bit_cast(unsigned int, hi);
            dst[(x4 * 4 + 2) * C_] = o;
            lo.x = (_Float16)a.w; lo.y = (_Float16)e.w;
            hi.x = (_Float16)f.w; hi.y = (_Float16)g.w;
            o.x = __builtin_bit_cast(unsigned int, lo);
            o.y = __builtin_bit_cast(unsigned int, hi);
            dst[(x4 * 4 + 3) * C_] = o;
        }
        return;
    }

    {                                        // ---- zero outS ----
        int t = (bid - PREP_T) * 256 + tid;  // < 200,704
        float4 z = {0.0f, 0.0f, 0.0f, 0.0f};
        float4* dst = (float4*)(ws_f + F_OUTS);
        dst[t * 2]     = z;
        dst[t * 2 + 1] = z;
    }
}

// ---------------------------------------------------------------------------
// k_main: block = (b, n, j) (R6-proven chunking). IN-BLOCK weight generation
// (R14-verified math): 14 threads sample into column-private LDS cells (no
// races), packed to half2 by 224 threads — no global weight arrays, no prep
// weight job. Then the R15-proven y4/x-quad dot2 loop with LDS weights.
// Epilogue: live-px coalesced atomics into outS [py][px][c].
__global__ __launch_bounds__(256, 4) void k_main(const float* __restrict__ ws_f,
                                                 const float* __restrict__ boxes,
                                                 const float* __restrict__ gt,
                                                 float* __restrict__ outs) {
    __shared__ float        s_wyf[H_][WROW_];      // 1792 B fp32 y staging
    __shared__ unsigned int s_wy2[Y2_ * WROW_];    //  896 B packed half2
    __shared__ float        s_ax[W_][WROW_];       // 1792 B fp32 x-weights

    int bid = blockIdx.x;
    int j   = bid % JPN_;
    int n   = (bid / JPN_) & (N_ - 1);
    int b   = bid / (JPN_ * N_);
    int k, s;
    if (j == 0) { k = 0; s = 0; }
    else        { k = 1 + ((j - 1) >> 2); s = (j - 1) & 3; }
    int tid  = (int)threadIdx.x;
    int lane = tid & 63;
    int rg   = tid >> 6;
    int c    = rg * 64 + lane;

    // ---- roi coords (wave-uniform scalar loads) ----
    const float* bp = boxes + ((size_t)b * N_ + n) * 4;
    float bx1, by1, bx2, by2;
    if (k == 0) {
        bx1 = bp[0]; by1 = bp[1]; bx2 = bp[2]; by2 = bp[3];
    } else {
        const float* gp = gt + ((size_t)b * M_ + (k - 1)) * 4;
        bx1 = fminf(bp[0], gp[0]); by1 = fminf(bp[1], gp[1]);
        bx2 = fmaxf(bp[2], gp[2]); by2 = fmaxf(bp[3], gp[3]);
    }
    float rw = fmaxf(bx2 - bx1, 1.0f);
    float rh = fmaxf(by2 - by1, 1.0f);

    // ---- in-block weight generation ----
    for (int e = tid; e < H_ * WROW_; e += 256) ((float*)s_wyf)[e] = 0.0f;
    for (int e = tid; e < W_ * WROW_; e += 256) ((float*)s_ax)[e] = 0.0f;
    __syncthreads();

    if (tid < P_) {                          // y samples, column-private
        int p = tid;
        float bin = rh / 7.0f;
        float gf  = ceilf(bin);
        int   g   = (int)gf;
        float ivg = 1.0f / gf;
        float start = by1 + (float)p * bin;
        for (int ss = 0; ss < g; ++ss) {
            float coord = start + ((float)ss + 0.5f) * bin * ivg;
            if (coord < -1.0f || coord > (float)H_) continue;
            float cc = fmaxf(coord, 0.0f);
            int low = (int)floorf(cc);
            int high; float l;
            if (low >= H_ - 1) { low = H_ - 1; high = H_ - 1; l = 0.0f; }
            else               { high = low + 1; l = cc - (float)low; }
            s_wyf[low][p]  += (1.0f - l) * ivg;
            s_wyf[high][p] += l * ivg;
        }
    } else if (tid >= 64 && tid < 64 + P_) { // x samples, column-private
        int p = tid - 64;
        float bin = rw / 7.0f;
        float gf  = ceilf(bin);
        int   g   = (int)gf;
        float ivg = 1.0f / gf;
        float fs  = (k == 0) ? ivg : ivg * (1.0f / (float)M_);
        float start = bx1 + (float)p * bin;
        for (int ss = 0; ss < g; ++ss) {
            float coord = start + ((float)ss + 0.5f) * bin * ivg;
            if (coord < -1.0f || coord > (float)W_) continue;
            float cc = fmaxf(coord, 0.0f);
            int low = (int)floorf(cc);
            int high; float l;
            if (low >= W_ - 1) { low = W_ - 1; high = W_ - 1; l = 0.0f; }
            else               { high = low + 1; l = cc - (float)low; }
            s_ax[low][p]  += (1.0f - l) * fs;
            s_ax[high][p] += l * fs;
        }
    }
    __syncthreads();

    if (tid < Y2_ * WROW_) {                 // pack y fp32 pairs -> half2
        int q2 = tid >> 3, col = tid & 7;
        half2v h;
        if (col < P_) { h.x = (_Float16)s_wyf[2 * q2][col]; h.y = (_Float16)s_wyf[2 * q2 + 1][col]; }
        else          { h.x = (_Float16)0.0f; h.y = (_Float16)0.0f; }
        s_wy2[tid] = __builtin_bit_cast(unsigned int, h);
    }
    __syncthreads();

    // ---- chunk bounds (uniform per-thread arithmetic, no metadata) ----
    int xlo = min(max((int)floorf(fmaxf(bx1, 0.0f)), 0), W_ - 1);
    int xhi = min(max((int)floorf(bx1 + rw) + 1, 0), W_ - 1) + 1;
    int ylo = min(max((int)floorf(fmaxf(by1, 0.0f)), 0), H_ - 1);
    int yhi = min(max((int)floorf(by1 + rh) + 1, 0), H_ - 1) + 1;
    int xs, xe;
    if (k == 0) { xs = xlo; xe = xhi; }
    else {
        int cw = (xhi - xlo + SCTX_ - 1) >> 2;
        xs = xlo + s * cw;
        xe = min(xs + cw, xhi);
    }
    if (xs >= xe) return;                    // block-uniform, after all barriers

    int ylo4 = ylo >> 2;                     // quad range covering [ylo,yhi)
    int yhi4 = (yhi + 3) >> 2;               // extra rows have zero weight

    const uint2* f4 = (const uint2*)ws_f + (size_t)b * (Y4_ * W_ * C_);

    float acc[49];
#pragma unroll
    for (int q = 0; q < 49; ++q) acc[q] = 0.0f;
    int live = 0;

    for (int x = xs; x < xe; x += 4) {
        float cs[4][P_];
#pragma unroll
        for (int i = 0; i < 4; ++i)
#pragma unroll
            for (int py = 0; py < P_; ++py) cs[i][py] = 0.0f;

        // x+1..x+3 over-reads past xe/roi edge stay inside d_ws (spill into
        // the outS region at worst); garbage never enters acc (gated on xe).
        const uint2* cp = f4 + ((size_t)(ylo4 * W_ + x)) * C_ + c;
        for (int y4 = ylo4; y4 < yhi4; ++y4) {
            uint2 d0 = cp[0];
            uint2 d1 = cp[C_];
            uint2 d2 = cp[2 * C_];
            uint2 d3 = cp[3 * C_];
            uint4 wa0 = *(const uint4*)&s_wy2[(2 * y4) * WROW_];
            uint4 wb0 = *(const uint4*)&s_wy2[(2 * y4) * WROW_ + 4];
            uint4 wa1 = *(const uint4*)&s_wy2[(2 * y4 + 1) * WROW_];
            uint4 wb1 = *(const uint4*)&s_wy2[(2 * y4 + 1) * WROW_ + 4];
            half2v w0[7], w1[7];
            w0[0] = __builtin_bit_cast(half2v, wa0.x);
            w0[1] = __builtin_bit_cast(half2v, wa0.y);
            w0[2] = __builtin_bit_cast(half2v, wa0.z);
            w0[3] = __builtin_bit_cast(half2v, wa0.w);
            w0[4] = __builtin_bit_cast(half2v, wb0.x);
            w0[5] = __builtin_bit_cast(half2v, wb0.y);
            w0[6] = __builtin_bit_cast(half2v, wb0.z);
            w1[0] = __builtin_bit_cast(half2v, wa1.x);
            w1[1] = __builtin_bit_cast(half2v, wa1.y);
            w1[2] = __builtin_bit_cast(half2v, wa1.z);
            w1[3] = __builtin_bit_cast(half2v, wa1.w);
            w1[4] = __builtin_bit_cast(half2v, wb1.x);
            w1[5] = __builtin_bit_cast(half2v, wb1.y);
            w1[6] = __builtin_bit_cast(half2v, wb1.z);
            half2v v0a = __builtin_bit_cast(half2v, d0.x);
            half2v v0b = __builtin_bit_cast(half2v, d0.y);
            half2v v1a = __builtin_bit_cast(half2v, d1.x);
            half2v v1b = __builtin_bit_cast(half2v, d1.y);
            half2v v2a = __builtin_bit_cast(half2v, d2.x);
            half2v v2b = __builtin_bit_cast(half2v, d2.y);
            half2v v3a = __builtin_bit_cast(half2v, d3.x);
            half2v v3b = __builtin_bit_cast(half2v, d3.y);
#pragma unroll
            for (int py = 0; py < P_; ++py) {
                cs[0][py] = FDOT2(w1[py], v0b, FDOT2(w0[py], v0a, cs[0][py]));
                cs[1][py] = FDOT2(w1[py], v1b, FDOT2(w0[py], v1a, cs[1][py]));
                cs[2][py] = FDOT2(w1[py], v2b, FDOT2(w0[py], v2a, cs[2][py]));
                cs[3][py] = FDOT2(w1[py], v3b, FDOT2(w0[py], v3a, cs[3][py]));
            }
            cp += W_ * C_;
        }

        // ---- x-stage (fp32, exact weights from LDS) ----
#pragma unroll
        for (int i = 0; i < 4; ++i) {
            if (x + i < xe) {                         // wave-uniform branch
                float av[8];
                *(float4*)(&av[0]) = *(const float4*)&s_ax[x + i][0];
                *(float4*)(&av[4]) = *(const float4*)&s_ax[x + i][4];
#pragma unroll
                for (int px = 0; px < P_; ++px) {
                    float w = av[px];
                    if (w != 0.0f) {
                        live |= 1 << px;
#pragma unroll
                        for (int py = 0; py < P_; ++py)
                            acc[py * P_ + px] = fmaf(w, cs[i][py], acc[py * P_ + px]);
                    }
                }
            }
        }
    }

    // ---- epilogue: live-px coalesced wave-atomics into outS ----
    float* os = outs + ((size_t)b * N_ + n) * (49 * C_) + c;
#pragma unroll
    for (int px = 0; px < P_; ++px) {
        if (live & (1 << px)) {
#pragma unroll
            for (int py = 0; py < P_; ++py)
                atomicAdd(os + (py * P_ + px) * C_, acc[py * P_ + px]);
        }
    }
}

// ---------------------------------------------------------------------------
// k_final: outS [b][n][py][px][c] -> out [b][n][c][py][px] via padded LDS.
__global__ __launch_bounds__(256) void k_final(const float* __restrict__ outs,
                                               float* __restrict__ out) {
    __shared__ float t[49 * 257];        // pad 257: conflict-free transpose read
    int bn  = blockIdx.x;                // 0..B*N-1
    int tid = (int)threadIdx.x;
    const float* src = outs + (size_t)bn * (49 * C_);
    for (int e = tid; e < 49 * C_; e += 256) {
        int q = e >> 8, c = e & 255;
        t[q * 257 + c] = src[e];         // coalesced read
    }
    __syncthreads();
    float* dst = out + (size_t)bn * (C_ * 49);
    for (int e = tid; e < C_ * 49; e += 256) {
        int c = e / 49, q = e % 49;
        dst[e] = t[q * 257 + c];         // coalesced write
    }
}

// ---------------------------------------------------------------------------
extern "C" void kernel_launch(void* const* d_in, const int* in_sizes, int n_in,
                              void* d_out, int out_size, void* d_ws, size_t ws_size,
                              hipStream_t stream) {
    const float* fm    = (const float*)d_in[0];
    const float* boxes = (const float*)d_in[1];
    const float* gt    = (const float*)d_in[2];
    float* ws_f = (float*)d_ws;
    float* out  = (float*)d_out;
    float* outs = ws_f + F_OUTS;

    k_prep<<<PREP_N, 256, 0, stream>>>(fm, ws_f);
    k_main<<<B_ * N_ * JPN_, 256, 0, stream>>>(ws_f, boxes, gt, outs);
    k_final<<<B_ * N_, 256, 0, stream>>>(outs, out);
}